// Round 5
// baseline (760.905 us; speedup 1.0000x reference)
//
#include <hip/hip_runtime.h>
#include <math.h>

#define LN_EPS 1e-5f

typedef float v2f  __attribute__((ext_vector_type(2)));
typedef float f32x4 __attribute__((ext_vector_type(4)));
typedef short s16x8 __attribute__((ext_vector_type(8)));   // 8 bf16 in 4 VGPRs (guide §3)

__device__ __forceinline__ v2f pf(v2f a, v2f b, v2f c) {
    return __builtin_elementwise_fma(a, b, c);
}
__device__ __forceinline__ v2f bc2(float s) { v2f r; r.x = s; r.y = s; return r; }

// fp32 -> bf16 (RNE), bf16 -> fp32
__device__ __forceinline__ short f2bf(float f) {
    union { float f; unsigned u; } v; v.f = f;
    return (short)((v.u + 0x7fffu + ((v.u >> 16) & 1u)) >> 16);
}
__device__ __forceinline__ float bf2f(short s) {
    union { unsigned u; float f; } v; v.u = ((unsigned)(unsigned short)s) << 16;
    return v.f;
}

// LayerNorm over 2*D2 values held as v2f[D2], then *g+b, then ReLU (in place).
template<int D2>
__device__ __forceinline__ void ln_relu2(v2f (&v)[D2],
                                         const float* __restrict__ g,
                                         const float* __restrict__ b) {
    const float invD = 1.0f / (float)(2 * D2);
    float m = 0.f;
#pragma unroll
    for (int i = 0; i < D2; ++i) m += v[i].x + v[i].y;
    m *= invD;
    float var = 0.f;
#pragma unroll
    for (int i = 0; i < D2; ++i) {
        float dx = v[i].x - m, dy = v[i].y - m;
        var = fmaf(dx, dx, var);
        var = fmaf(dy, dy, var);
    }
    var *= invD;
    const float rs = rsqrtf(var + LN_EPS);
    const v2f* g2 = (const v2f*)g;
    const v2f* b2 = (const v2f*)b;
#pragma unroll
    for (int i = 0; i < D2; ++i) {
        v2f t = pf((v[i] - m) * rs, g2[i], b2[i]);
        v[i].x = fmaxf(t.x, 0.f);
        v[i].y = fmaxf(t.y, 0.f);
    }
}

// k-outer matvec (all OUT2 accumulators live).
template<int IN2, int OUT2>
__device__ __forceinline__ void mv2(const v2f (&x)[IN2],
                                    const float* __restrict__ W,
                                    v2f (&y)[OUT2]) {
    const v2f* W2 = (const v2f*)W;
#pragma unroll
    for (int j = 0; j < OUT2; ++j) y[j] = bc2(0.f);
#pragma unroll
    for (int k2 = 0; k2 < IN2; ++k2) {
        const v2f x0 = bc2(x[k2].x), x1 = bc2(x[k2].y);
#pragma unroll
        for (int j = 0; j < OUT2; ++j) {
            y[j] = pf(x0, W2[(2 * k2) * OUT2 + j], y[j]);
            y[j] = pf(x1, W2[(2 * k2 + 1) * OUT2 + j], y[j]);
        }
    }
}

template<int IN2, int OUT2>
__device__ __forceinline__ void mv2_bias(const v2f (&x)[IN2],
                                         const float* __restrict__ W,
                                         const float* __restrict__ bias,
                                         v2f (&y)[OUT2]) {
    const v2f* W2 = (const v2f*)W;
    const v2f* b2 = (const v2f*)bias;
#pragma unroll
    for (int j = 0; j < OUT2; ++j) y[j] = b2[j];
#pragma unroll
    for (int k2 = 0; k2 < IN2; ++k2) {
        const v2f x0 = bc2(x[k2].x), x1 = bc2(x[k2].y);
#pragma unroll
        for (int j = 0; j < OUT2; ++j) {
            y[j] = pf(x0, W2[(2 * k2) * OUT2 + j], y[j]);
            y[j] = pf(x1, W2[(2 * k2 + 1) * OUT2 + j], y[j]);
        }
    }
}

// j-outer matvec (+bias): one accumulator live at a time; per-output
// accumulation order (k ascending) identical to mv2/mv2_bias -> bitwise-same.
template<int IN2, int OUT2>
__device__ __forceinline__ void mv2j_bias(const v2f (&x)[IN2],
                                          const float* __restrict__ W,
                                          const float* __restrict__ bias,
                                          v2f (&y)[OUT2]) {
    const v2f* W2 = (const v2f*)W;
    const v2f* b2 = (const v2f*)bias;
#pragma unroll
    for (int j = 0; j < OUT2; ++j) {
        v2f acc = b2[j];
#pragma unroll
        for (int k2 = 0; k2 < IN2; ++k2) {
            acc = pf(bc2(x[k2].x), W2[(2 * k2) * OUT2 + j], acc);
            acc = pf(bc2(x[k2].y), W2[(2 * k2 + 1) * OUT2 + j], acc);
        }
        y[j] = acc;
    }
}

template<int IN2, int OUT2>
__device__ __forceinline__ void mv2j(const v2f (&x)[IN2],
                                     const float* __restrict__ W,
                                     v2f (&y)[OUT2]) {
    const v2f* W2 = (const v2f*)W;
#pragma unroll
    for (int j = 0; j < OUT2; ++j) {
        v2f acc = bc2(0.f);
#pragma unroll
        for (int k2 = 0; k2 < IN2; ++k2) {
            acc = pf(bc2(x[k2].x), W2[(2 * k2) * OUT2 + j], acc);
            acc = pf(bc2(x[k2].y), W2[(2 * k2 + 1) * OUT2 + j], acc);
        }
        y[j] = acc;
    }
}

// ============================================================================
// STAGE KERNEL — MFMA only. Computes rep@kw1 and rep@rw1[0:128] (pre-LN, bf16)
// and writes them row-major to workspace.
// TOOLCHAIN RULE (3x confirmed r1/r3/r4): __launch_bounds__ 2nd arg sets a
// TOTAL unified budget of 512/arg per wave, split evenly arch/accum:
//   arg=4 -> 64 arch VGPRs -> spills any ~120-live kernel (even w/o MFMA!)
//   arg=2 -> 128 arch VGPRs -> fits this kernel's ~110 live set. USE 2 ONLY.
// MFMA layouts (guide §3, HW-verified m89/m91/m120):
//   A[m=lane&15][k=quad*8+j]  B[k=quad*8+j][n=lane&15]  D: col=lane&15,row=quad*4+reg
// ============================================================================
__global__ __launch_bounds__(256, 2) void opening_critic_stage(
    const float* __restrict__ rep,
    const float* __restrict__ kw1, const float* __restrict__ rw1,
    short* __restrict__ o1, short* __restrict__ o2, int nloc)
{
    __shared__ __align__(16) short scratch[4][64][72];   // per-wave C->row transpose

    const int tid  = threadIdx.x;
    const int wave = tid >> 6, lane = tid & 63;
    const int waveRow0 = blockIdx.x * 256 + wave * 64;
    const int myrow    = waveRow0 + lane;
    const int lm = lane & 15, quad = lane >> 4;

    // A-fragments resident (loaded once, used for BOTH weight matrices)
    s16x8 afr[4][4];
#pragma unroll
    for (int rt = 0; rt < 4; ++rt) {
        int arow = waveRow0 + rt * 16 + lm;
        if (arow >= nloc) arow = nloc - 1;
        const float* ap = rep + (size_t)arow * 128 + quad * 8;
#pragma unroll
        for (int kc = 0; kc < 4; ++kc) {
            const float4 x0 = *(const float4*)(ap + kc * 32);
            const float4 x1 = *(const float4*)(ap + kc * 32 + 4);
            s16x8 t;
            t[0] = f2bf(x0.x); t[1] = f2bf(x0.y); t[2] = f2bf(x0.z); t[3] = f2bf(x0.w);
            t[4] = f2bf(x1.x); t[5] = f2bf(x1.y); t[6] = f2bf(x1.z); t[7] = f2bf(x1.w);
            afr[rt][kc] = t;
        }
    }

#pragma unroll 1
    for (int w = 0; w < 2; ++w) {
        const float* __restrict__ W = w ? rw1 : kw1;
        short* __restrict__ O = w ? o2 : o1;

        // ct-outer: one column-tile's B-fragments live at a time
#pragma unroll
        for (int ct = 0; ct < 4; ++ct) {
            s16x8 bfr[4];
#pragma unroll
            for (int kc = 0; kc < 4; ++kc) {
                const float* wp = W + (size_t)(kc * 32 + quad * 8) * 64 + ct * 16 + lm;
                s16x8 t;
#pragma unroll
                for (int j = 0; j < 8; ++j) t[j] = f2bf(wp[j * 64]);
                bfr[kc] = t;
            }
#pragma unroll
            for (int rt = 0; rt < 4; ++rt) {
                f32x4 acc = (f32x4){0.f, 0.f, 0.f, 0.f};
#pragma unroll
                for (int kc = 0; kc < 4; ++kc)
                    acc = __builtin_amdgcn_mfma_f32_16x16x32_bf16(
                        afr[rt][kc], bfr[kc], acc, 0, 0, 0);
                // scatter D (C-layout) to wave-private scratch, bf16
#pragma unroll
                for (int reg = 0; reg < 4; ++reg)
                    scratch[wave][rt * 16 + quad * 4 + reg][ct * 16 + lm] = f2bf(acc[reg]);
            }
        }

        // intra-wave exchange: scatter writes drained, gather own row, store.
        asm volatile("s_waitcnt lgkmcnt(0)" ::: "memory");
        if (myrow < nloc) {
            const s16x8* sr = (const s16x8*)scratch[wave][lane];
            s16x8* dst = (s16x8*)(O + (size_t)myrow * 64);
#pragma unroll
            for (int i = 0; i < 8; ++i) dst[i] = sr[i];   // 8 x (ds_read_b128 + dwordx4 store)
        }
        asm volatile("s_waitcnt lgkmcnt(0)" ::: "memory");  // reads done before scratch reuse
    }
}

// ============================================================================
// TAIL KERNEL — pure VALU, no LDS, no MFMA.
// Round-4 post-mortem: (256,4) -> arch VGPR 64 EVEN WITHOUT MFMA -> ~300 MB
// spill writes, 274 us. Per the 512/arg unified-budget rule, (256,2) grants
// 128 arch VGPRs (live ~120 fits, no spill); the pin is only a compiler
// budget floor, so with 128 VGPRs + 0 AGPR + 0 LDS the HW still co-residents
// 4 waves/SIMD (16 waves/CU, ~50% occupancy).
// ============================================================================
__global__ __launch_bounds__(256, 2) void opening_critic_tail(
    const short* __restrict__ o1, const short* __restrict__ o2,
    const float* __restrict__ pose, const float* __restrict__ opening,
    const float* __restrict__ kg,  const float* __restrict__ kb,
    const float* __restrict__ kw2, const float* __restrict__ kb2,
    const float* __restrict__ qw1, const float* __restrict__ qg,  const float* __restrict__ qb,
    const float* __restrict__ qw2, const float* __restrict__ qb2,
    const float* __restrict__ vw1, const float* __restrict__ vg,  const float* __restrict__ vb,
    const float* __restrict__ vw2, const float* __restrict__ vb2,
    const float* __restrict__ aw1, const float* __restrict__ ag,  const float* __restrict__ ab,
    const float* __restrict__ aw2, const float* __restrict__ ab2,
    const float* __restrict__ rw1, const float* __restrict__ rg1, const float* __restrict__ rb1,
    const float* __restrict__ rw2, const float* __restrict__ rg2, const float* __restrict__ rb2,
    const float* __restrict__ rw3, const float* __restrict__ rb3,
    const float* __restrict__ gw1, const float* __restrict__ gg,  const float* __restrict__ gb,
    const float* __restrict__ gw2, const float* __restrict__ gb2,
    float* __restrict__ out, int nloc)
{
    const int myrow = blockIdx.x * 256 + threadIdx.x;
    if (myrow >= nloc) return;   // no barriers/LDS -> early exit is safe

    float pv[6];
#pragma unroll
    for (int i = 0; i < 6; ++i) pv[i] = pose[(size_t)myrow * 6 + i];
    const float ov = opening[myrow];

    // ---------------- key branch from staged row ----------------
    v2f key[16];
    {
        v2f ka[32];
        const s16x8* r1 = (const s16x8*)(o1 + (size_t)myrow * 64);
#pragma unroll
        for (int i = 0; i < 8; ++i) {
            const s16x8 t = r1[i];
#pragma unroll
            for (int j = 0; j < 4; ++j) {
                v2f u; u.x = bf2f(t[2 * j]); u.y = bf2f(t[2 * j + 1]);
                ka[i * 4 + j] = u;
            }
        }
        ln_relu2<32>(ka, kg, kb);
        mv2j_bias<32, 16>(ka, kw2, kb2, key);   // j-outer: ka 64 + key fill
    }

    // query 6->16 (LN/ReLU), then FUSED j-outer query@qw2 * key -> s
    v2f s[16];
    {
        v2f q1[8];
        const v2f* qw1_2 = (const v2f*)qw1;
#pragma unroll
        for (int j = 0; j < 8; ++j) q1[j] = bc2(0.f);
#pragma unroll
        for (int k = 0; k < 6; ++k) {
            const v2f xv = bc2(pv[k]);
#pragma unroll
            for (int j = 0; j < 8; ++j) q1[j] = pf(xv, qw1_2[k * 8 + j], q1[j]);
        }
        ln_relu2<8>(q1, qg, qb);
        const v2f* W2 = (const v2f*)qw2;
        const v2f* b2 = (const v2f*)qb2;
#pragma unroll
        for (int j = 0; j < 16; ++j) {
            v2f acc = b2[j];
#pragma unroll
            for (int k2 = 0; k2 < 8; ++k2) {
                acc = pf(bc2(q1[k2].x), W2[(2 * k2) * 16 + j], acc);
                acc = pf(bc2(q1[k2].y), W2[(2 * k2 + 1) * 16 + j], acc);
            }
            s[j] = acc * key[j];                 // key[j] dies here
        }
    }

    // softmax over s (32 values)
    float mx = -1e30f;
#pragma unroll
    for (int j = 0; j < 16; ++j) mx = fmaxf(mx, fmaxf(s[j].x, s[j].y));
    float sum = 0.f;
#pragma unroll
    for (int j = 0; j < 16; ++j) {
        s[j].x = __expf(s[j].x - mx);
        s[j].y = __expf(s[j].y - mx);
        sum += s[j].x + s[j].y;
    }
    const float inv = 1.0f / sum;

    // value 1->16 (LN/ReLU), FUSED j-outer value@vw2 applied to s
    {
        v2f v1[8];
        const v2f* vw1_2 = (const v2f*)vw1;
        const v2f xo = bc2(ov);
#pragma unroll
        for (int j = 0; j < 8; ++j) v1[j] = xo * vw1_2[j];
        ln_relu2<8>(v1, vg, vb);
        const v2f* W2 = (const v2f*)vw2;
        const v2f* b2 = (const v2f*)vb2;
#pragma unroll
        for (int j = 0; j < 16; ++j) {
            v2f acc = b2[j];
#pragma unroll
            for (int k2 = 0; k2 < 8; ++k2) {
                acc = pf(bc2(v1[k2].x), W2[(2 * k2) * 16 + j], acc);
                acc = pf(bc2(v1[k2].y), W2[(2 * k2 + 1) * 16 + j], acc);
            }
            s[j] = s[j] * inv * acc;
        }
    }

    // attention head: 32 -> 32 -> 16   (only att[8] survives past here)
    v2f att[8];
    {
        v2f a1[16];
        mv2<16, 16>(s, aw1, a1);
        ln_relu2<16>(a1, ag, ab);
        mv2_bias<16, 8>(a1, aw2, ab2, att);
    }

    // ---------------- residual branch from staged row ----------------
    v2f residuals[8];
    {
        v2f ra[32];
        const s16x8* r2 = (const s16x8*)(o2 + (size_t)myrow * 64);
#pragma unroll
        for (int i = 0; i < 8; ++i) {
            const s16x8 t = r2[i];
#pragma unroll
            for (int j = 0; j < 4; ++j) {
                v2f u; u.x = bf2f(t[2 * j]); u.y = bf2f(t[2 * j + 1]);
                ra[i * 4 + j] = u;
            }
        }
#pragma unroll
        for (int kk = 0; kk < 6; ++kk) {
            const v2f* w = (const v2f*)(rw1 + (128 + kk) * 64);
            const v2f xv = bc2(pv[kk]);
#pragma unroll
            for (int j = 0; j < 32; ++j) ra[j] = pf(xv, w[j], ra[j]);
        }
        {
            const v2f* w = (const v2f*)(rw1 + 134 * 64);
            const v2f xo = bc2(ov);
#pragma unroll
            for (int j = 0; j < 32; ++j) ra[j] = pf(xo, w[j], ra[j]);
        }
        ln_relu2<32>(ra, rg1, rb1);
        v2f h2[16];
        mv2j<32, 16>(ra, rw2, h2);               // j-outer: ra 64 + h2 32 + att 16 peak
        ln_relu2<16>(h2, rg2, rb2);
        mv2_bias<16, 8>(h2, rw3, rb3, residuals);
    }

    // get_value on concat([att, residuals]): 32 -> 16 -> 1
    float score;
    {
        v2f g1[8];
        const v2f* gw1_2 = (const v2f*)gw1;
#pragma unroll
        for (int j = 0; j < 8; ++j) g1[j] = bc2(0.f);
#pragma unroll
        for (int k2 = 0; k2 < 8; ++k2) {
            const v2f x0 = bc2(att[k2].x), x1 = bc2(att[k2].y);
#pragma unroll
            for (int j = 0; j < 8; ++j) {
                g1[j] = pf(x0, gw1_2[(2 * k2) * 8 + j], g1[j]);
                g1[j] = pf(x1, gw1_2[(2 * k2 + 1) * 8 + j], g1[j]);
            }
        }
#pragma unroll
        for (int k2 = 0; k2 < 8; ++k2) {
            const v2f x0 = bc2(residuals[k2].x), x1 = bc2(residuals[k2].y);
#pragma unroll
            for (int j = 0; j < 8; ++j) {
                g1[j] = pf(x0, gw1_2[(16 + 2 * k2) * 8 + j], g1[j]);
                g1[j] = pf(x1, gw1_2[(16 + 2 * k2 + 1) * 8 + j], g1[j]);
            }
        }
        ln_relu2<8>(g1, gg, gb);
        score = gb2[0];
        const v2f* gw2_2 = (const v2f*)gw2;
#pragma unroll
        for (int k = 0; k < 8; ++k) {
            score = fmaf(g1[k].x, gw2_2[k].x, score);
            score = fmaf(g1[k].y, gw2_2[k].y, score);
        }
    }

    out[myrow] = score;
}

extern "C" void kernel_launch(void* const* d_in, const int* in_sizes, int n_in,
                              void* d_out, int out_size, void* d_ws, size_t ws_size,
                              hipStream_t stream) {
    const float* rep     = (const float*)d_in[0];
    const float* pose    = (const float*)d_in[1];
    const float* opening = (const float*)d_in[2];
    const float* kw1 = (const float*)d_in[3];
    const float* kg  = (const float*)d_in[4];
    const float* kb  = (const float*)d_in[5];
    const float* kw2 = (const float*)d_in[6];
    const float* kb2 = (const float*)d_in[7];
    const float* qw1 = (const float*)d_in[8];
    const float* qg  = (const float*)d_in[9];
    const float* qb  = (const float*)d_in[10];
    const float* qw2 = (const float*)d_in[11];
    const float* qb2 = (const float*)d_in[12];
    const float* vw1 = (const float*)d_in[13];
    const float* vg  = (const float*)d_in[14];
    const float* vb  = (const float*)d_in[15];
    const float* vw2 = (const float*)d_in[16];
    const float* vb2 = (const float*)d_in[17];
    const float* aw1 = (const float*)d_in[18];
    const float* ag  = (const float*)d_in[19];
    const float* ab  = (const float*)d_in[20];
    const float* aw2 = (const float*)d_in[21];
    const float* ab2 = (const float*)d_in[22];
    const float* rw1 = (const float*)d_in[23];
    const float* rg1 = (const float*)d_in[24];
    const float* rb1 = (const float*)d_in[25];
    const float* rw2 = (const float*)d_in[26];
    const float* rg2 = (const float*)d_in[27];
    const float* rb2 = (const float*)d_in[28];
    const float* rw3 = (const float*)d_in[29];
    const float* rb3 = (const float*)d_in[30];
    const float* gw1 = (const float*)d_in[31];
    const float* gg  = (const float*)d_in[32];
    const float* gb  = (const float*)d_in[33];
    const float* gw2 = (const float*)d_in[34];
    const float* gb2 = (const float*)d_in[35];

    const int n = in_sizes[0] / 128;   // 524288 rows
    float* out = (float*)d_out;

    // Workspace: 2 bf16 rows of 64 per sample = 256 B/row. Chunk if ws is small.
    const size_t perRowBytes = 2 * 64 * sizeof(short);
    const long long cap = (long long)(ws_size / perRowBytes);
    int C;
    if (cap >= (long long)n) C = n;
    else {
        C = (int)((cap / 256) * 256);
        if (C < 256) C = 256;   // workspace is expected to be far larger than 64 KB
    }
    short* o1 = (short*)d_ws;
    short* o2 = o1 + (size_t)C * 64;

    dim3 block(256);
    for (int r0 = 0; r0 < n; r0 += C) {
        const int nloc = (n - r0 < C) ? (n - r0) : C;
        dim3 grid((nloc + 255) / 256);
        hipLaunchKernelGGL(opening_critic_stage, grid, block, 0, stream,
                           rep + (size_t)r0 * 128, kw1, rw1, o1, o2, nloc);
        hipLaunchKernelGGL(opening_critic_tail, grid, block, 0, stream,
                           o1, o2, pose + (size_t)r0 * 6, opening + r0,
                           kg, kb, kw2, kb2,
                           qw1, qg, qb, qw2, qb2,
                           vw1, vg, vb, vw2, vb2,
                           aw1, ag, ab, aw2, ab2,
                           rw1, rg1, rb1, rw2, rg2, rb2, rw3, rb3,
                           gw1, gg, gb, gw2, gb2,
                           out + r0, nloc);
    }
}

// Round 6
// 683.194 us; speedup vs baseline: 1.1137x; 1.1137x over previous
//
#include <hip/hip_runtime.h>
#include <math.h>

#define LN_EPS 1e-5f

typedef float v2f  __attribute__((ext_vector_type(2)));
typedef float f32x4 __attribute__((ext_vector_type(4)));
typedef short s16x8 __attribute__((ext_vector_type(8)));   // 8 bf16 in 4 VGPRs (guide §3)

__device__ __forceinline__ v2f pf(v2f a, v2f b, v2f c) {
    return __builtin_elementwise_fma(a, b, c);
}
__device__ __forceinline__ v2f bc2(float s) { v2f r; r.x = s; r.y = s; return r; }
__device__ __forceinline__ v2f vmax2(v2f a, v2f b) {
    v2f r; r.x = fmaxf(a.x, b.x); r.y = fmaxf(a.y, b.y); return r;
}

// fp32 -> bf16 (RNE), bf16 -> fp32
__device__ __forceinline__ short f2bf(float f) {
    union { float f; unsigned u; } v; v.f = f;
    return (short)((v.u + 0x7fffu + ((v.u >> 16) & 1u)) >> 16);
}
__device__ __forceinline__ float bf2f(short s) {
    union { unsigned u; float f; } v; v.u = ((unsigned)(unsigned short)s) << 16;
    return v.f;
}

// LayerNorm over 2*D2 values held as v2f[D2], then *g+b, then ReLU (in place).
// ILP shape (round-5 post-mortem): mean/var as 4 packed-v2f partial chains
// (v_pk_add_f32 / packed fma) instead of one serial 64-add chain. Reassociation
// perturbs ~1e-6 rel — far below the bf16-dominated absmax (0.0078).
template<int D2>
__device__ __forceinline__ void ln_relu2(v2f (&v)[D2],
                                         const float* __restrict__ g,
                                         const float* __restrict__ b) {
    const float invD = 1.0f / (float)(2 * D2);
    v2f p0 = bc2(0.f), p1 = bc2(0.f), p2 = bc2(0.f), p3 = bc2(0.f);
#pragma unroll
    for (int i = 0; i < D2; i += 4) {
        p0 += v[i]; p1 += v[i + 1]; p2 += v[i + 2]; p3 += v[i + 3];
    }
    const v2f ps = (p0 + p1) + (p2 + p3);
    const float m = (ps.x + ps.y) * invD;
    const v2f mm = bc2(m);
    v2f q0 = bc2(0.f), q1 = bc2(0.f), q2 = bc2(0.f), q3 = bc2(0.f);
#pragma unroll
    for (int i = 0; i < D2; i += 4) {
        const v2f d0 = v[i] - mm, d1 = v[i + 1] - mm;
        const v2f d2 = v[i + 2] - mm, d3 = v[i + 3] - mm;
        q0 = pf(d0, d0, q0); q1 = pf(d1, d1, q1);
        q2 = pf(d2, d2, q2); q3 = pf(d3, d3, q3);
    }
    const v2f qs = (q0 + q1) + (q2 + q3);
    const float var = (qs.x + qs.y) * invD;
    const float rs = rsqrtf(var + LN_EPS);
    const v2f* g2 = (const v2f*)g;
    const v2f* b2 = (const v2f*)b;
#pragma unroll
    for (int i = 0; i < D2; ++i) {
        v2f t = pf((v[i] - mm) * rs, g2[i], b2[i]);
        v[i].x = fmaxf(t.x, 0.f);
        v[i].y = fmaxf(t.y, 0.f);
    }
}

// k-outer matvec: OUT2 independent accumulator chains -> high ILP.
// (round-5 post-mortem: j-outer variants were serial chains, VALUBusy 28%.)
template<int IN2, int OUT2>
__device__ __forceinline__ void mv2(const v2f (&x)[IN2],
                                    const float* __restrict__ W,
                                    v2f (&y)[OUT2]) {
    const v2f* W2 = (const v2f*)W;
#pragma unroll
    for (int j = 0; j < OUT2; ++j) y[j] = bc2(0.f);
#pragma unroll
    for (int k2 = 0; k2 < IN2; ++k2) {
        const v2f x0 = bc2(x[k2].x), x1 = bc2(x[k2].y);
#pragma unroll
        for (int j = 0; j < OUT2; ++j) {
            y[j] = pf(x0, W2[(2 * k2) * OUT2 + j], y[j]);
            y[j] = pf(x1, W2[(2 * k2 + 1) * OUT2 + j], y[j]);
        }
    }
}

template<int IN2, int OUT2>
__device__ __forceinline__ void mv2_bias(const v2f (&x)[IN2],
                                         const float* __restrict__ W,
                                         const float* __restrict__ bias,
                                         v2f (&y)[OUT2]) {
    const v2f* W2 = (const v2f*)W;
    const v2f* b2 = (const v2f*)bias;
#pragma unroll
    for (int j = 0; j < OUT2; ++j) y[j] = b2[j];
#pragma unroll
    for (int k2 = 0; k2 < IN2; ++k2) {
        const v2f x0 = bc2(x[k2].x), x1 = bc2(x[k2].y);
#pragma unroll
        for (int j = 0; j < OUT2; ++j) {
            y[j] = pf(x0, W2[(2 * k2) * OUT2 + j], y[j]);
            y[j] = pf(x1, W2[(2 * k2 + 1) * OUT2 + j], y[j]);
        }
    }
}

// ============================================================================
// STAGE KERNEL — MFMA only (unchanged from round 5; no spill signature).
// Computes rep@kw1 and rep@rw1[0:128] (pre-LN, bf16) -> workspace rows.
// TOOLCHAIN RULES (6 rounds of evidence):
//   * __launch_bounds__ 2nd arg: arg=4 -> 64 arch VGPRs (spills ~120-live
//     kernels, even without MFMA); arg=2 -> 128 arch. USE 2 ONLY.
//   * Occupancy law: resident waves/SIMD ~= 512 / (2 * arch_VGPR) — the
//     unified RF charges ~2x the reported arch count. 86..128 VGPR -> 2
//     waves/SIMD regardless; optimize ILP, not occupancy, in that band.
// MFMA layouts (guide §3, HW-verified m89/m91/m120):
//   A[m=lane&15][k=quad*8+j]  B[k=quad*8+j][n=lane&15]  D: col=lane&15,row=quad*4+reg
// ============================================================================
__global__ __launch_bounds__(256, 2) void opening_critic_stage(
    const float* __restrict__ rep,
    const float* __restrict__ kw1, const float* __restrict__ rw1,
    short* __restrict__ o1, short* __restrict__ o2, int nloc)
{
    __shared__ __align__(16) short scratch[4][64][72];   // per-wave C->row transpose

    const int tid  = threadIdx.x;
    const int wave = tid >> 6, lane = tid & 63;
    const int waveRow0 = blockIdx.x * 256 + wave * 64;
    const int myrow    = waveRow0 + lane;
    const int lm = lane & 15, quad = lane >> 4;

    // A-fragments resident (loaded once, used for BOTH weight matrices)
    s16x8 afr[4][4];
#pragma unroll
    for (int rt = 0; rt < 4; ++rt) {
        int arow = waveRow0 + rt * 16 + lm;
        if (arow >= nloc) arow = nloc - 1;
        const float* ap = rep + (size_t)arow * 128 + quad * 8;
#pragma unroll
        for (int kc = 0; kc < 4; ++kc) {
            const float4 x0 = *(const float4*)(ap + kc * 32);
            const float4 x1 = *(const float4*)(ap + kc * 32 + 4);
            s16x8 t;
            t[0] = f2bf(x0.x); t[1] = f2bf(x0.y); t[2] = f2bf(x0.z); t[3] = f2bf(x0.w);
            t[4] = f2bf(x1.x); t[5] = f2bf(x1.y); t[6] = f2bf(x1.z); t[7] = f2bf(x1.w);
            afr[rt][kc] = t;
        }
    }

#pragma unroll 1
    for (int w = 0; w < 2; ++w) {
        const float* __restrict__ W = w ? rw1 : kw1;
        short* __restrict__ O = w ? o2 : o1;

        // ct-outer: one column-tile's B-fragments live at a time
#pragma unroll
        for (int ct = 0; ct < 4; ++ct) {
            s16x8 bfr[4];
#pragma unroll
            for (int kc = 0; kc < 4; ++kc) {
                const float* wp = W + (size_t)(kc * 32 + quad * 8) * 64 + ct * 16 + lm;
                s16x8 t;
#pragma unroll
                for (int j = 0; j < 8; ++j) t[j] = f2bf(wp[j * 64]);
                bfr[kc] = t;
            }
#pragma unroll
            for (int rt = 0; rt < 4; ++rt) {
                f32x4 acc = (f32x4){0.f, 0.f, 0.f, 0.f};
#pragma unroll
                for (int kc = 0; kc < 4; ++kc)
                    acc = __builtin_amdgcn_mfma_f32_16x16x32_bf16(
                        afr[rt][kc], bfr[kc], acc, 0, 0, 0);
                // scatter D (C-layout) to wave-private scratch, bf16
#pragma unroll
                for (int reg = 0; reg < 4; ++reg)
                    scratch[wave][rt * 16 + quad * 4 + reg][ct * 16 + lm] = f2bf(acc[reg]);
            }
        }

        // intra-wave exchange: scatter writes drained, gather own row, store.
        asm volatile("s_waitcnt lgkmcnt(0)" ::: "memory");
        if (myrow < nloc) {
            const s16x8* sr = (const s16x8*)scratch[wave][lane];
            s16x8* dst = (s16x8*)(O + (size_t)myrow * 64);
#pragma unroll
            for (int i = 0; i < 8; ++i) dst[i] = sr[i];   // 8 x (ds_read_b128 + dwordx4 store)
        }
        asm volatile("s_waitcnt lgkmcnt(0)" ::: "memory");  // reads done before scratch reuse
    }
}

// ============================================================================
// TAIL KERNEL — pure VALU, no LDS, no MFMA, pinned (256,2) = 128 arch VGPRs.
// Round-5 post-mortem: occupancy is pinned at 2 waves/SIMD for any 86..128
// VGPR live-set (2x-charge law), so this version maximizes ILP instead:
//   * k-outer matvecs (16 independent accumulator chains) — r0-proven layout
//     that fits 128 VGPRs spill-free;
//   * tree reductions in LN / softmax (4 packed partials; fmax tree is exact);
//   * o2 staged-row load issued right after softmax so L2/L3 latency hides
//     under the value + attention-head compute (~1500 MACs).
// ============================================================================
__global__ __launch_bounds__(256, 2) void opening_critic_tail(
    const short* __restrict__ o1, const short* __restrict__ o2,
    const float* __restrict__ pose, const float* __restrict__ opening,
    const float* __restrict__ kg,  const float* __restrict__ kb,
    const float* __restrict__ kw2, const float* __restrict__ kb2,
    const float* __restrict__ qw1, const float* __restrict__ qg,  const float* __restrict__ qb,
    const float* __restrict__ qw2, const float* __restrict__ qb2,
    const float* __restrict__ vw1, const float* __restrict__ vg,  const float* __restrict__ vb,
    const float* __restrict__ vw2, const float* __restrict__ vb2,
    const float* __restrict__ aw1, const float* __restrict__ ag,  const float* __restrict__ ab,
    const float* __restrict__ aw2, const float* __restrict__ ab2,
    const float* __restrict__ rw1, const float* __restrict__ rg1, const float* __restrict__ rb1,
    const float* __restrict__ rw2, const float* __restrict__ rg2, const float* __restrict__ rb2,
    const float* __restrict__ rw3, const float* __restrict__ rb3,
    const float* __restrict__ gw1, const float* __restrict__ gg,  const float* __restrict__ gb,
    const float* __restrict__ gw2, const float* __restrict__ gb2,
    float* __restrict__ out, int nloc)
{
    const int myrow = blockIdx.x * 256 + threadIdx.x;
    if (myrow >= nloc) return;   // no barriers/LDS -> early exit is safe

    float pv[6];
#pragma unroll
    for (int i = 0; i < 6; ++i) pv[i] = pose[(size_t)myrow * 6 + i];
    const float ov = opening[myrow];

    // ---------------- key branch from staged row ----------------
    v2f key[16];
    {
        v2f ka[32];
        const s16x8* r1 = (const s16x8*)(o1 + (size_t)myrow * 64);
#pragma unroll
        for (int i = 0; i < 8; ++i) {
            const s16x8 t = r1[i];
#pragma unroll
            for (int j = 0; j < 4; ++j) {
                v2f u; u.x = bf2f(t[2 * j]); u.y = bf2f(t[2 * j + 1]);
                ka[i * 4 + j] = u;
            }
        }
        ln_relu2<32>(ka, kg, kb);
        mv2_bias<32, 16>(ka, kw2, kb2, key);   // k-outer: 16 indep chains
    }

    // query: 6 -> 16 -> 32, then s = query * key elementwise
    v2f s[16];
    {
        v2f q1[8];
        const v2f* qw1_2 = (const v2f*)qw1;
#pragma unroll
        for (int j = 0; j < 8; ++j) q1[j] = bc2(0.f);
#pragma unroll
        for (int k = 0; k < 6; ++k) {
            const v2f xv = bc2(pv[k]);
#pragma unroll
            for (int j = 0; j < 8; ++j) q1[j] = pf(xv, qw1_2[k * 8 + j], q1[j]);
        }
        ln_relu2<8>(q1, qg, qb);
        v2f query[16];
        mv2_bias<8, 16>(q1, qw2, qb2, query);
#pragma unroll
        for (int j = 0; j < 16; ++j) s[j] = query[j] * key[j];   // key/query die
    }

    // softmax over s (32 values): exact fmax tree + 4-partial sum
    float mx;
    {
        v2f t8[8];
#pragma unroll
        for (int j = 0; j < 8; ++j) t8[j] = vmax2(s[j], s[j + 8]);
        v2f t4a = vmax2(t8[0], t8[4]), t4b = vmax2(t8[1], t8[5]);
        v2f t4c = vmax2(t8[2], t8[6]), t4d = vmax2(t8[3], t8[7]);
        v2f t2 = vmax2(vmax2(t4a, t4b), vmax2(t4c, t4d));
        mx = fmaxf(t2.x, t2.y);
    }
    float sum;
    {
        v2f p0 = bc2(0.f), p1 = bc2(0.f), p2 = bc2(0.f), p3 = bc2(0.f);
#pragma unroll
        for (int j = 0; j < 16; j += 4) {
            s[j].x     = __expf(s[j].x - mx);     s[j].y     = __expf(s[j].y - mx);
            s[j + 1].x = __expf(s[j + 1].x - mx); s[j + 1].y = __expf(s[j + 1].y - mx);
            s[j + 2].x = __expf(s[j + 2].x - mx); s[j + 2].y = __expf(s[j + 2].y - mx);
            s[j + 3].x = __expf(s[j + 3].x - mx); s[j + 3].y = __expf(s[j + 3].y - mx);
            p0 += s[j]; p1 += s[j + 1]; p2 += s[j + 2]; p3 += s[j + 3];
        }
        const v2f ps = (p0 + p1) + (p2 + p3);
        sum = ps.x + ps.y;
    }
    const float inv = 1.0f / sum;

    // issue the o2 staged-row load NOW; consumed after the attention head,
    // so ~500cy of L2/L3 latency hides under value+att (~1500 MACs).
    s16x8 raw2[8];
    {
        const s16x8* r2 = (const s16x8*)(o2 + (size_t)myrow * 64);
#pragma unroll
        for (int i = 0; i < 8; ++i) raw2[i] = r2[i];
    }

    // value: 1 -> 16 -> 32, applied to s
    {
        v2f v1[8];
        const v2f* vw1_2 = (const v2f*)vw1;
        const v2f xo = bc2(ov);
#pragma unroll
        for (int j = 0; j < 8; ++j) v1[j] = xo * vw1_2[j];
        ln_relu2<8>(v1, vg, vb);
        v2f value[16];
        mv2_bias<8, 16>(v1, vw2, vb2, value);
#pragma unroll
        for (int j = 0; j < 16; ++j) s[j] = s[j] * inv * value[j];
    }

    // attention head: 32 -> 32 -> 16   (only att[8] survives past here)
    v2f att[8];
    {
        v2f a1[16];
        mv2<16, 16>(s, aw1, a1);
        ln_relu2<16>(a1, ag, ab);
        mv2_bias<16, 8>(a1, aw2, ab2, att);
    }

    // ---------------- residual branch from staged row ----------------
    v2f residuals[8];
    {
        v2f ra[32];
#pragma unroll
        for (int i = 0; i < 8; ++i) {
            const s16x8 t = raw2[i];
#pragma unroll
            for (int j = 0; j < 4; ++j) {
                v2f u; u.x = bf2f(t[2 * j]); u.y = bf2f(t[2 * j + 1]);
                ra[i * 4 + j] = u;
            }
        }
#pragma unroll
        for (int kk = 0; kk < 6; ++kk) {
            const v2f* w = (const v2f*)(rw1 + (128 + kk) * 64);
            const v2f xv = bc2(pv[kk]);
#pragma unroll
            for (int j = 0; j < 32; ++j) ra[j] = pf(xv, w[j], ra[j]);
        }
        {
            const v2f* w = (const v2f*)(rw1 + 134 * 64);
            const v2f xo = bc2(ov);
#pragma unroll
            for (int j = 0; j < 32; ++j) ra[j] = pf(xo, w[j], ra[j]);
        }
        ln_relu2<32>(ra, rg1, rb1);
        v2f h2[16];
        mv2<32, 16>(ra, rw2, h2);                // k-outer (r0-proven fit)
        ln_relu2<16>(h2, rg2, rb2);
        mv2_bias<16, 8>(h2, rw3, rb3, residuals);
    }

    // get_value on concat([att, residuals]): 32 -> 16 -> 1
    float score;
    {
        v2f g1[8];
        const v2f* gw1_2 = (const v2f*)gw1;
#pragma unroll
        for (int j = 0; j < 8; ++j) g1[j] = bc2(0.f);
#pragma unroll
        for (int k2 = 0; k2 < 8; ++k2) {
            const v2f x0 = bc2(att[k2].x), x1 = bc2(att[k2].y);
#pragma unroll
            for (int j = 0; j < 8; ++j) {
                g1[j] = pf(x0, gw1_2[(2 * k2) * 8 + j], g1[j]);
                g1[j] = pf(x1, gw1_2[(2 * k2 + 1) * 8 + j], g1[j]);
            }
        }
#pragma unroll
        for (int k2 = 0; k2 < 8; ++k2) {
            const v2f x0 = bc2(residuals[k2].x), x1 = bc2(residuals[k2].y);
#pragma unroll
            for (int j = 0; j < 8; ++j) {
                g1[j] = pf(x0, gw1_2[(16 + 2 * k2) * 8 + j], g1[j]);
                g1[j] = pf(x1, gw1_2[(16 + 2 * k2 + 1) * 8 + j], g1[j]);
            }
        }
        ln_relu2<8>(g1, gg, gb);
        score = gb2[0];
        const v2f* gw2_2 = (const v2f*)gw2;
#pragma unroll
        for (int k = 0; k < 8; ++k) {
            score = fmaf(g1[k].x, gw2_2[k].x, score);
            score = fmaf(g1[k].y, gw2_2[k].y, score);
        }
    }

    out[myrow] = score;
}

extern "C" void kernel_launch(void* const* d_in, const int* in_sizes, int n_in,
                              void* d_out, int out_size, void* d_ws, size_t ws_size,
                              hipStream_t stream) {
    const float* rep     = (const float*)d_in[0];
    const float* pose    = (const float*)d_in[1];
    const float* opening = (const float*)d_in[2];
    const float* kw1 = (const float*)d_in[3];
    const float* kg  = (const float*)d_in[4];
    const float* kb  = (const float*)d_in[5];
    const float* kw2 = (const float*)d_in[6];
    const float* kb2 = (const float*)d_in[7];
    const float* qw1 = (const float*)d_in[8];
    const float* qg  = (const float*)d_in[9];
    const float* qb  = (const float*)d_in[10];
    const float* qw2 = (const float*)d_in[11];
    const float* qb2 = (const float*)d_in[12];
    const float* vw1 = (const float*)d_in[13];
    const float* vg  = (const float*)d_in[14];
    const float* vb  = (const float*)d_in[15];
    const float* vw2 = (const float*)d_in[16];
    const float* vb2 = (const float*)d_in[17];
    const float* aw1 = (const float*)d_in[18];
    const float* ag  = (const float*)d_in[19];
    const float* ab  = (const float*)d_in[20];
    const float* aw2 = (const float*)d_in[21];
    const float* ab2 = (const float*)d_in[22];
    const float* rw1 = (const float*)d_in[23];
    const float* rg1 = (const float*)d_in[24];
    const float* rb1 = (const float*)d_in[25];
    const float* rw2 = (const float*)d_in[26];
    const float* rg2 = (const float*)d_in[27];
    const float* rb2 = (const float*)d_in[28];
    const float* rw3 = (const float*)d_in[29];
    const float* rb3 = (const float*)d_in[30];
    const float* gw1 = (const float*)d_in[31];
    const float* gg  = (const float*)d_in[32];
    const float* gb  = (const float*)d_in[33];
    const float* gw2 = (const float*)d_in[34];
    const float* gb2 = (const float*)d_in[35];

    const int n = in_sizes[0] / 128;   // 524288 rows
    float* out = (float*)d_out;

    // Workspace: 2 bf16 rows of 64 per sample = 256 B/row. Chunk if ws is small.
    const size_t perRowBytes = 2 * 64 * sizeof(short);
    const long long cap = (long long)(ws_size / perRowBytes);
    int C;
    if (cap >= (long long)n) C = n;
    else {
        C = (int)((cap / 256) * 256);
        if (C < 256) C = 256;   // workspace is expected to be far larger than 64 KB
    }
    short* o1 = (short*)d_ws;
    short* o2 = o1 + (size_t)C * 64;

    dim3 block(256);
    for (int r0 = 0; r0 < n; r0 += C) {
        const int nloc = (n - r0 < C) ? (n - r0) : C;
        dim3 grid((nloc + 255) / 256);
        hipLaunchKernelGGL(opening_critic_stage, grid, block, 0, stream,
                           rep + (size_t)r0 * 128, kw1, rw1, o1, o2, nloc);
        hipLaunchKernelGGL(opening_critic_tail, grid, block, 0, stream,
                           o1, o2, pose + (size_t)r0 * 6, opening + r0,
                           kg, kb, kw2, kb2,
                           qw1, qg, qb, qw2, qb2,
                           vw1, vg, vb, vw2, vb2,
                           aw1, ag, ab, aw2, ab2,
                           rw1, rg1, rb1, rw2, rg2, rb2, rw3, rb3,
                           gw1, gg, gb, gw2, gb2,
                           out + r0, nloc);
    }
}

// Round 7
// 554.800 us; speedup vs baseline: 1.3715x; 1.2314x over previous
//
#include <hip/hip_runtime.h>
#include <math.h>

#define LN_EPS 1e-5f

typedef float v2f  __attribute__((ext_vector_type(2)));
typedef float f32x4 __attribute__((ext_vector_type(4)));
typedef short s16x8 __attribute__((ext_vector_type(8)));   // 8 bf16 in 4 VGPRs (guide §3)

__device__ __forceinline__ v2f pf(v2f a, v2f b, v2f c) {
    return __builtin_elementwise_fma(a, b, c);
}
__device__ __forceinline__ v2f bc2(float s) { v2f r; r.x = s; r.y = s; return r; }
__device__ __forceinline__ v2f vmax2(v2f a, v2f b) {
    v2f r; r.x = fmaxf(a.x, b.x); r.y = fmaxf(a.y, b.y); return r;
}

// fp32 -> bf16 (RNE), bf16 -> fp32
__device__ __forceinline__ short f2bf(float f) {
    union { float f; unsigned u; } v; v.f = f;
    return (short)((v.u + 0x7fffu + ((v.u >> 16) & 1u)) >> 16);
}
__device__ __forceinline__ float bf2f(short s) {
    union { unsigned u; float f; } v; v.u = ((unsigned)(unsigned short)s) << 16;
    return v.f;
}

// LayerNorm over 2*D2 values held as v2f[D2], then *g+b, then ReLU (in place).
// 4 packed partial chains (ILP; round-5 lesson).
template<int D2>
__device__ __forceinline__ void ln_relu2(v2f (&v)[D2],
                                         const float* __restrict__ g,
                                         const float* __restrict__ b) {
    const float invD = 1.0f / (float)(2 * D2);
    v2f p0 = bc2(0.f), p1 = bc2(0.f), p2 = bc2(0.f), p3 = bc2(0.f);
#pragma unroll
    for (int i = 0; i < D2; i += 4) {
        p0 += v[i]; p1 += v[i + 1]; p2 += v[i + 2]; p3 += v[i + 3];
    }
    const v2f ps = (p0 + p1) + (p2 + p3);
    const float m = (ps.x + ps.y) * invD;
    const v2f mm = bc2(m);
    v2f q0 = bc2(0.f), q1 = bc2(0.f), q2 = bc2(0.f), q3 = bc2(0.f);
#pragma unroll
    for (int i = 0; i < D2; i += 4) {
        const v2f d0 = v[i] - mm, d1 = v[i + 1] - mm;
        const v2f d2 = v[i + 2] - mm, d3 = v[i + 3] - mm;
        q0 = pf(d0, d0, q0); q1 = pf(d1, d1, q1);
        q2 = pf(d2, d2, q2); q3 = pf(d3, d3, q3);
    }
    const v2f qs = (q0 + q1) + (q2 + q3);
    const float var = (qs.x + qs.y) * invD;
    const float rs = rsqrtf(var + LN_EPS);
    const v2f* g2 = (const v2f*)g;
    const v2f* b2 = (const v2f*)b;
#pragma unroll
    for (int i = 0; i < D2; ++i) {
        v2f t = pf((v[i] - mm) * rs, g2[i], b2[i]);
        v[i].x = fmaxf(t.x, 0.f);
        v[i].y = fmaxf(t.y, 0.f);
    }
}

// k-outer matvec: OUT2 independent accumulator chains -> high ILP (r6-proven).
template<int IN2, int OUT2>
__device__ __forceinline__ void mv2(const v2f (&x)[IN2],
                                    const float* __restrict__ W,
                                    v2f (&y)[OUT2]) {
    const v2f* W2 = (const v2f*)W;
#pragma unroll
    for (int j = 0; j < OUT2; ++j) y[j] = bc2(0.f);
#pragma unroll
    for (int k2 = 0; k2 < IN2; ++k2) {
        const v2f x0 = bc2(x[k2].x), x1 = bc2(x[k2].y);
#pragma unroll
        for (int j = 0; j < OUT2; ++j) {
            y[j] = pf(x0, W2[(2 * k2) * OUT2 + j], y[j]);
            y[j] = pf(x1, W2[(2 * k2 + 1) * OUT2 + j], y[j]);
        }
    }
}

template<int IN2, int OUT2>
__device__ __forceinline__ void mv2_bias(const v2f (&x)[IN2],
                                         const float* __restrict__ W,
                                         const float* __restrict__ bias,
                                         v2f (&y)[OUT2]) {
    const v2f* W2 = (const v2f*)W;
    const v2f* b2 = (const v2f*)bias;
#pragma unroll
    for (int j = 0; j < OUT2; ++j) y[j] = b2[j];
#pragma unroll
    for (int k2 = 0; k2 < IN2; ++k2) {
        const v2f x0 = bc2(x[k2].x), x1 = bc2(x[k2].y);
#pragma unroll
        for (int j = 0; j < OUT2; ++j) {
            y[j] = pf(x0, W2[(2 * k2) * OUT2 + j], y[j]);
            y[j] = pf(x1, W2[(2 * k2 + 1) * OUT2 + j], y[j]);
        }
    }
}

// ---- stage building blocks -------------------------------------------------
// MFMA layouts (guide §3, HW-verified m89/m91/m120):
//   A[m=lane&15][k=quad*8+j]  B[k=quad*8+j][n=lane&15]  D: col=lane&15,row=quad*4+reg

// matmul1: X[64 rows x 128] (afr) @ W1[128][64] -> scratch rows (bf16, pre-LN)
__device__ __forceinline__ void mm1(const s16x8 (&afr)[4][4],
                                    const float* __restrict__ W1,
                                    int lm, int quad,
                                    short (*__restrict__ sc)[72]) {
#pragma unroll
    for (int ct = 0; ct < 4; ++ct) {
        s16x8 bfr[4];
#pragma unroll
        for (int kc = 0; kc < 4; ++kc) {
            const float* wp = W1 + (size_t)(kc * 32 + quad * 8) * 64 + ct * 16 + lm;
            s16x8 t;
#pragma unroll
            for (int j = 0; j < 8; ++j) t[j] = f2bf(wp[j * 64]);
            bfr[kc] = t;
        }
#pragma unroll
        for (int rt = 0; rt < 4; ++rt) {
            f32x4 acc = (f32x4){0.f, 0.f, 0.f, 0.f};
#pragma unroll
            for (int kc = 0; kc < 4; ++kc)
                acc = __builtin_amdgcn_mfma_f32_16x16x32_bf16(
                    afr[rt][kc], bfr[kc], acc, 0, 0, 0);
#pragma unroll
            for (int reg = 0; reg < 4; ++reg)
                sc[rt * 16 + quad * 4 + reg][ct * 16 + lm] = f2bf(acc[reg]);
        }
    }
}

// matmul2: h[64 rows x 64] (bf16, in scratch) @ W2[64][32] -> scratch (bf16)
__device__ __forceinline__ void mm2(const float* __restrict__ W2,
                                    int lm, int quad,
                                    short (*__restrict__ sc)[72]) {
    s16x8 a2[4][2];
#pragma unroll
    for (int rt = 0; rt < 4; ++rt)
#pragma unroll
        for (int kc = 0; kc < 2; ++kc)
            a2[rt][kc] = *(const s16x8*)&sc[rt * 16 + lm][kc * 32 + quad * 8];
    // reads must land in regs before the D-scatter below overwrites scratch
    asm volatile("s_waitcnt lgkmcnt(0)" ::: "memory");
#pragma unroll
    for (int ct = 0; ct < 2; ++ct) {
        s16x8 b2[2];
#pragma unroll
        for (int kc = 0; kc < 2; ++kc) {
            const float* wp = W2 + (size_t)(kc * 32 + quad * 8) * 32 + ct * 16 + lm;
            s16x8 t;
#pragma unroll
            for (int j = 0; j < 8; ++j) t[j] = f2bf(wp[j * 32]);
            b2[kc] = t;
        }
#pragma unroll
        for (int rt = 0; rt < 4; ++rt) {
            f32x4 acc = (f32x4){0.f, 0.f, 0.f, 0.f};
            acc = __builtin_amdgcn_mfma_f32_16x16x32_bf16(a2[rt][0], b2[0], acc, 0, 0, 0);
            acc = __builtin_amdgcn_mfma_f32_16x16x32_bf16(a2[rt][1], b2[1], acc, 0, 0, 0);
#pragma unroll
            for (int reg = 0; reg < 4; ++reg)
                sc[rt * 16 + quad * 4 + reg][ct * 16 + lm] = f2bf(acc[reg]);
        }
    }
}

// ============================================================================
// STAGE KERNEL — all MFMA work. Per 64-row wave:
//   key chain:  rep@kw1 -> LN+ReLU -> @kw2            -> o1 (32 bf16/row)
//   res chain:  rep@rw1 + pose/open fold -> LN+ReLU -> @rw2 -> o2 (32 bf16/row)
// This moves the tail's two fat matvecs (4096 of ~8100 MACs/row) onto the
// matrix pipe and halves ws traffic.
// TOOLCHAIN RULES (6 rounds of evidence):
//   * __launch_bounds__ 2nd arg: arg=4 -> 64 arch VGPRs (spills ~120-live
//     kernels, even w/o MFMA); arg=2 -> 128 arch. USE 2 ONLY.
//   * Occupancy law: waves/SIMD ~= floor(512 / (2 * arch_VGPR)).
// Register discipline: key chain keeps its row bf16-resident (32 regs) since
// afr (64 regs) is still live; residual chain (afr dead) uses f32 rows.
// ============================================================================
__global__ __launch_bounds__(256, 2) void opening_critic_stage(
    const float* __restrict__ rep, const float* __restrict__ pose,
    const float* __restrict__ opening,
    const float* __restrict__ kw1, const float* __restrict__ kg,
    const float* __restrict__ kb,  const float* __restrict__ kw2,
    const float* __restrict__ rw1, const float* __restrict__ rg1,
    const float* __restrict__ rb1, const float* __restrict__ rw2,
    short* __restrict__ o1, short* __restrict__ o2, int nloc)
{
    __shared__ __align__(16) short scratch[4][64][72];   // per-wave transpose buffer

    const int tid  = threadIdx.x;
    const int wave = tid >> 6, lane = tid & 63;
    const int waveRow0 = blockIdx.x * 256 + wave * 64;
    const int myrow    = waveRow0 + lane;
    const int rowc     = (myrow < nloc) ? myrow : (nloc - 1);
    const int lm = lane & 15, quad = lane >> 4;
    short (*sc)[72] = scratch[wave];

    // per-row small inputs (residual fold) — issued early for latency slack
    float pv[6];
#pragma unroll
    for (int i = 0; i < 6; ++i) pv[i] = pose[(size_t)rowc * 6 + i];
    const float ov = opening[rowc];

    // A-fragments resident (loaded once, used by BOTH chains)
    s16x8 afr[4][4];
#pragma unroll
    for (int rt = 0; rt < 4; ++rt) {
        int arow = waveRow0 + rt * 16 + lm;
        if (arow >= nloc) arow = nloc - 1;
        const float* ap = rep + (size_t)arow * 128 + quad * 8;
#pragma unroll
        for (int kc = 0; kc < 4; ++kc) {
            const float4 x0 = *(const float4*)(ap + kc * 32);
            const float4 x1 = *(const float4*)(ap + kc * 32 + 4);
            s16x8 t;
            t[0] = f2bf(x0.x); t[1] = f2bf(x0.y); t[2] = f2bf(x0.z); t[3] = f2bf(x0.w);
            t[4] = f2bf(x1.x); t[5] = f2bf(x1.y); t[6] = f2bf(x1.z); t[7] = f2bf(x1.w);
            afr[rt][kc] = t;
        }
    }

    // ===================== key chain =====================
    mm1(afr, kw1, lm, quad, sc);
    asm volatile("s_waitcnt lgkmcnt(0)" ::: "memory");
    {
        // gather own row as bf16 (afr live -> keep row compact: 32 regs)
        s16x8 rowb[8];
        const s16x8* sr = (const s16x8*)sc[lane];
#pragma unroll
        for (int i = 0; i < 8; ++i) rowb[i] = sr[i];
        asm volatile("s_waitcnt lgkmcnt(0)" ::: "memory");   // reads done before rewrite

        // LN stats from bf16 values (identical values to the old tail path)
        v2f p0 = bc2(0.f), p1 = bc2(0.f), p2 = bc2(0.f), p3 = bc2(0.f);
#pragma unroll
        for (int i = 0; i < 8; ++i) {
            v2f u0, u1, u2, u3;
            u0.x = bf2f(rowb[i][0]); u0.y = bf2f(rowb[i][1]);
            u1.x = bf2f(rowb[i][2]); u1.y = bf2f(rowb[i][3]);
            u2.x = bf2f(rowb[i][4]); u2.y = bf2f(rowb[i][5]);
            u3.x = bf2f(rowb[i][6]); u3.y = bf2f(rowb[i][7]);
            p0 += u0; p1 += u1; p2 += u2; p3 += u3;
        }
        const v2f ps = (p0 + p1) + (p2 + p3);
        const float m = (ps.x + ps.y) * (1.0f / 64.0f);
        const v2f mm = bc2(m);
        v2f q0 = bc2(0.f), q1 = bc2(0.f), q2 = bc2(0.f), q3 = bc2(0.f);
#pragma unroll
        for (int i = 0; i < 8; ++i) {
            v2f u0, u1, u2, u3;
            u0.x = bf2f(rowb[i][0]); u0.y = bf2f(rowb[i][1]);
            u1.x = bf2f(rowb[i][2]); u1.y = bf2f(rowb[i][3]);
            u2.x = bf2f(rowb[i][4]); u2.y = bf2f(rowb[i][5]);
            u3.x = bf2f(rowb[i][6]); u3.y = bf2f(rowb[i][7]);
            const v2f d0 = u0 - mm, d1 = u1 - mm, d2 = u2 - mm, d3 = u3 - mm;
            q0 = pf(d0, d0, q0); q1 = pf(d1, d1, q1);
            q2 = pf(d2, d2, q2); q3 = pf(d3, d3, q3);
        }
        const v2f qs = (q0 + q1) + (q2 + q3);
        const float rs = rsqrtf((qs.x + qs.y) * (1.0f / 64.0f) + LN_EPS);

        // normalize + ReLU + quantize -> write h rows back into scratch
        s16x8* dl = (s16x8*)sc[lane];
#pragma unroll
        for (int i = 0; i < 8; ++i) {
            s16x8 h;
#pragma unroll
            for (int e = 0; e < 8; ++e) {
                const float x = bf2f(rowb[i][e]);
                const float t = fmaf((x - m) * rs, kg[i * 8 + e], kb[i * 8 + e]);
                h[e] = f2bf(fmaxf(t, 0.f));
            }
            dl[i] = h;
        }
    }
    asm volatile("s_waitcnt lgkmcnt(0)" ::: "memory");
    mm2(kw2, lm, quad, sc);
    asm volatile("s_waitcnt lgkmcnt(0)" ::: "memory");
    if (myrow < nloc) {
        const s16x8* s2 = (const s16x8*)sc[lane];
        s16x8* dst = (s16x8*)(o1 + (size_t)myrow * 32);
#pragma unroll
        for (int i = 0; i < 4; ++i) dst[i] = s2[i];
    }
    asm volatile("s_waitcnt lgkmcnt(0)" ::: "memory");

    // ===================== residual chain =====================
    mm1(afr, rw1, lm, quad, sc);       // afr's last use — dies here
    asm volatile("s_waitcnt lgkmcnt(0)" ::: "memory");
    {
        // gather own row in f32 (afr dead -> 64 regs available)
        v2f row[32];
        const short* sr = sc[lane];
#pragma unroll
        for (int c = 0; c < 32; ++c) {
            v2f t; t.x = bf2f(sr[2 * c]); t.y = bf2f(sr[2 * c + 1]);
            row[c] = t;
        }
        asm volatile("s_waitcnt lgkmcnt(0)" ::: "memory");

        // pose/opening fold: rows 128..134 of rw1 (same math/order as old tail)
#pragma unroll
        for (int kk = 0; kk < 6; ++kk) {
            const v2f* w = (const v2f*)(rw1 + (size_t)(128 + kk) * 64);
            const v2f xv = bc2(pv[kk]);
#pragma unroll
            for (int j = 0; j < 32; ++j) row[j] = pf(xv, w[j], row[j]);
        }
        {
            const v2f* w = (const v2f*)(rw1 + (size_t)134 * 64);
            const v2f xo = bc2(ov);
#pragma unroll
            for (int j = 0; j < 32; ++j) row[j] = pf(xo, w[j], row[j]);
        }
        ln_relu2<32>(row, rg1, rb1);

        // quantize h1 -> scratch
        s16x8* dl = (s16x8*)sc[lane];
#pragma unroll
        for (int i = 0; i < 8; ++i) {
            s16x8 h;
#pragma unroll
            for (int j = 0; j < 4; ++j) {
                h[2 * j]     = f2bf(row[i * 4 + j].x);
                h[2 * j + 1] = f2bf(row[i * 4 + j].y);
            }
            dl[i] = h;
        }
    }
    asm volatile("s_waitcnt lgkmcnt(0)" ::: "memory");
    mm2(rw2, lm, quad, sc);
    asm volatile("s_waitcnt lgkmcnt(0)" ::: "memory");
    if (myrow < nloc) {
        const s16x8* s2 = (const s16x8*)sc[lane];
        s16x8* dst = (s16x8*)(o2 + (size_t)myrow * 32);
#pragma unroll
        for (int i = 0; i < 4; ++i) dst[i] = s2[i];
    }
}

// ============================================================================
// TAIL KERNEL — pure VALU, no LDS, no MFMA, pinned (256,2) = 128 arch VGPRs.
// Work halved vs round 6: reads key_pre (o1) and h2_pre (o2) and runs only
// query/value/softmax/att-head/LN2+rw3/get_value (~3.7K MACs/row).
// ============================================================================
__global__ __launch_bounds__(256, 2) void opening_critic_tail(
    const short* __restrict__ o1, const short* __restrict__ o2,
    const float* __restrict__ pose, const float* __restrict__ opening,
    const float* __restrict__ kb2,
    const float* __restrict__ qw1, const float* __restrict__ qg,  const float* __restrict__ qb,
    const float* __restrict__ qw2, const float* __restrict__ qb2,
    const float* __restrict__ vw1, const float* __restrict__ vg,  const float* __restrict__ vb,
    const float* __restrict__ vw2, const float* __restrict__ vb2,
    const float* __restrict__ aw1, const float* __restrict__ ag,  const float* __restrict__ ab,
    const float* __restrict__ aw2, const float* __restrict__ ab2,
    const float* __restrict__ rg2, const float* __restrict__ rb2,
    const float* __restrict__ rw3, const float* __restrict__ rb3,
    const float* __restrict__ gw1, const float* __restrict__ gg,  const float* __restrict__ gb,
    const float* __restrict__ gw2, const float* __restrict__ gb2,
    float* __restrict__ out, int nloc)
{
    const int myrow = blockIdx.x * 256 + threadIdx.x;
    if (myrow >= nloc) return;   // no barriers/LDS -> early exit is safe

    float pv[6];
#pragma unroll
    for (int i = 0; i < 6; ++i) pv[i] = pose[(size_t)myrow * 6 + i];
    const float ov = opening[myrow];

    // key = staged key_pre + kb2
    v2f key[16];
    {
        const s16x8* r1 = (const s16x8*)(o1 + (size_t)myrow * 32);
        const v2f* b2 = (const v2f*)kb2;
#pragma unroll
        for (int i = 0; i < 4; ++i) {
            const s16x8 t = r1[i];
#pragma unroll
            for (int j = 0; j < 4; ++j) {
                v2f u; u.x = bf2f(t[2 * j]); u.y = bf2f(t[2 * j + 1]);
                key[i * 4 + j] = u + b2[i * 4 + j];
            }
        }
    }

    // query: 6 -> 16 -> 32, then s = query * key elementwise
    v2f s[16];
    {
        v2f q1[8];
        const v2f* qw1_2 = (const v2f*)qw1;
#pragma unroll
        for (int j = 0; j < 8; ++j) q1[j] = bc2(0.f);
#pragma unroll
        for (int k = 0; k < 6; ++k) {
            const v2f xv = bc2(pv[k]);
#pragma unroll
            for (int j = 0; j < 8; ++j) q1[j] = pf(xv, qw1_2[k * 8 + j], q1[j]);
        }
        ln_relu2<8>(q1, qg, qb);
        v2f query[16];
        mv2_bias<8, 16>(q1, qw2, qb2, query);
#pragma unroll
        for (int j = 0; j < 16; ++j) s[j] = query[j] * key[j];   // key/query die
    }

    // softmax over s (32 values): exact fmax tree + 4-partial sum
    float mx;
    {
        v2f t8[8];
#pragma unroll
        for (int j = 0; j < 8; ++j) t8[j] = vmax2(s[j], s[j + 8]);
        v2f t4a = vmax2(t8[0], t8[4]), t4b = vmax2(t8[1], t8[5]);
        v2f t4c = vmax2(t8[2], t8[6]), t4d = vmax2(t8[3], t8[7]);
        v2f t2 = vmax2(vmax2(t4a, t4b), vmax2(t4c, t4d));
        mx = fmaxf(t2.x, t2.y);
    }
    float sum;
    {
        v2f p0 = bc2(0.f), p1 = bc2(0.f), p2 = bc2(0.f), p3 = bc2(0.f);
#pragma unroll
        for (int j = 0; j < 16; j += 4) {
            s[j].x     = __expf(s[j].x - mx);     s[j].y     = __expf(s[j].y - mx);
            s[j + 1].x = __expf(s[j + 1].x - mx); s[j + 1].y = __expf(s[j + 1].y - mx);
            s[j + 2].x = __expf(s[j + 2].x - mx); s[j + 2].y = __expf(s[j + 2].y - mx);
            s[j + 3].x = __expf(s[j + 3].x - mx); s[j + 3].y = __expf(s[j + 3].y - mx);
            p0 += s[j]; p1 += s[j + 1]; p2 += s[j + 2]; p3 += s[j + 3];
        }
        const v2f ps = (p0 + p1) + (p2 + p3);
        sum = ps.x + ps.y;
    }
    const float inv = 1.0f / sum;

    // issue the h2_pre staged-row load NOW; consumed after the attention head.
    s16x8 rawh[4];
    {
        const s16x8* r2 = (const s16x8*)(o2 + (size_t)myrow * 32);
#pragma unroll
        for (int i = 0; i < 4; ++i) rawh[i] = r2[i];
    }

    // value: 1 -> 16 -> 32, applied to s
    {
        v2f v1[8];
        const v2f* vw1_2 = (const v2f*)vw1;
        const v2f xo = bc2(ov);
#pragma unroll
        for (int j = 0; j < 8; ++j) v1[j] = xo * vw1_2[j];
        ln_relu2<8>(v1, vg, vb);
        v2f value[16];
        mv2_bias<8, 16>(v1, vw2, vb2, value);
#pragma unroll
        for (int j = 0; j < 16; ++j) s[j] = s[j] * inv * value[j];
    }

    // attention head: 32 -> 32 -> 16   (only att[8] survives past here)
    v2f att[8];
    {
        v2f a1[16];
        mv2<16, 16>(s, aw1, a1);
        ln_relu2<16>(a1, ag, ab);
        mv2_bias<16, 8>(a1, aw2, ab2, att);
    }

    // residual finish: LN2(h2_pre) -> rw3
    v2f residuals[8];
    {
        v2f h2[16];
#pragma unroll
        for (int i = 0; i < 4; ++i) {
            const s16x8 t = rawh[i];
#pragma unroll
            for (int j = 0; j < 4; ++j) {
                v2f u; u.x = bf2f(t[2 * j]); u.y = bf2f(t[2 * j + 1]);
                h2[i * 4 + j] = u;
            }
        }
        ln_relu2<16>(h2, rg2, rb2);
        mv2_bias<16, 8>(h2, rw3, rb3, residuals);
    }

    // get_value on concat([att, residuals]): 32 -> 16 -> 1
    float score;
    {
        v2f g1[8];
        const v2f* gw1_2 = (const v2f*)gw1;
#pragma unroll
        for (int j = 0; j < 8; ++j) g1[j] = bc2(0.f);
#pragma unroll
        for (int k2 = 0; k2 < 8; ++k2) {
            const v2f x0 = bc2(att[k2].x), x1 = bc2(att[k2].y);
#pragma unroll
            for (int j = 0; j < 8; ++j) {
                g1[j] = pf(x0, gw1_2[(2 * k2) * 8 + j], g1[j]);
                g1[j] = pf(x1, gw1_2[(2 * k2 + 1) * 8 + j], g1[j]);
            }
        }
#pragma unroll
        for (int k2 = 0; k2 < 8; ++k2) {
            const v2f x0 = bc2(residuals[k2].x), x1 = bc2(residuals[k2].y);
#pragma unroll
            for (int j = 0; j < 8; ++j) {
                g1[j] = pf(x0, gw1_2[(16 + 2 * k2) * 8 + j], g1[j]);
                g1[j] = pf(x1, gw1_2[(16 + 2 * k2 + 1) * 8 + j], g1[j]);
            }
        }
        ln_relu2<8>(g1, gg, gb);
        score = gb2[0];
        const v2f* gw2_2 = (const v2f*)gw2;
#pragma unroll
        for (int k = 0; k < 8; ++k) {
            score = fmaf(g1[k].x, gw2_2[k].x, score);
            score = fmaf(g1[k].y, gw2_2[k].y, score);
        }
    }

    out[myrow] = score;
}

extern "C" void kernel_launch(void* const* d_in, const int* in_sizes, int n_in,
                              void* d_out, int out_size, void* d_ws, size_t ws_size,
                              hipStream_t stream) {
    const float* rep     = (const float*)d_in[0];
    const float* pose    = (const float*)d_in[1];
    const float* opening = (const float*)d_in[2];
    const float* kw1 = (const float*)d_in[3];
    const float* kg  = (const float*)d_in[4];
    const float* kb  = (const float*)d_in[5];
    const float* kw2 = (const float*)d_in[6];
    const float* kb2 = (const float*)d_in[7];
    const float* qw1 = (const float*)d_in[8];
    const float* qg  = (const float*)d_in[9];
    const float* qb  = (const float*)d_in[10];
    const float* qw2 = (const float*)d_in[11];
    const float* qb2 = (const float*)d_in[12];
    const float* vw1 = (const float*)d_in[13];
    const float* vg  = (const float*)d_in[14];
    const float* vb  = (const float*)d_in[15];
    const float* vw2 = (const float*)d_in[16];
    const float* vb2 = (const float*)d_in[17];
    const float* aw1 = (const float*)d_in[18];
    const float* ag  = (const float*)d_in[19];
    const float* ab  = (const float*)d_in[20];
    const float* aw2 = (const float*)d_in[21];
    const float* ab2 = (const float*)d_in[22];
    const float* rw1 = (const float*)d_in[23];
    const float* rg1 = (const float*)d_in[24];
    const float* rb1 = (const float*)d_in[25];
    const float* rw2 = (const float*)d_in[26];
    const float* rg2 = (const float*)d_in[27];
    const float* rb2 = (const float*)d_in[28];
    const float* rw3 = (const float*)d_in[29];
    const float* rb3 = (const float*)d_in[30];
    const float* gw1 = (const float*)d_in[31];
    const float* gg  = (const float*)d_in[32];
    const float* gb  = (const float*)d_in[33];
    const float* gw2 = (const float*)d_in[34];
    const float* gb2 = (const float*)d_in[35];

    const int n = in_sizes[0] / 128;   // 524288 rows
    float* out = (float*)d_out;

    // Workspace: 2 bf16 rows of 32 per sample = 128 B/row. Chunk if ws is small.
    const size_t perRowBytes = 2 * 32 * sizeof(short);
    const long long cap = (long long)(ws_size / perRowBytes);
    int C;
    if (cap >= (long long)n) C = n;
    else {
        C = (int)((cap / 256) * 256);
        if (C < 256) C = 256;   // workspace is expected to be far larger than 32 KB
    }
    short* o1 = (short*)d_ws;
    short* o2 = o1 + (size_t)C * 32;

    dim3 block(256);
    for (int r0 = 0; r0 < n; r0 += C) {
        const int nloc = (n - r0 < C) ? (n - r0) : C;
        dim3 grid((nloc + 255) / 256);
        hipLaunchKernelGGL(opening_critic_stage, grid, block, 0, stream,
                           rep + (size_t)r0 * 128, pose + (size_t)r0 * 6, opening + r0,
                           kw1, kg, kb, kw2,
                           rw1, rg1, rb1, rw2,
                           o1, o2, nloc);
        hipLaunchKernelGGL(opening_critic_tail, grid, block, 0, stream,
                           o1, o2, pose + (size_t)r0 * 6, opening + r0,
                           kb2,
                           qw1, qg, qb, qw2, qb2,
                           vw1, vg, vb, vw2, vb2,
                           aw1, ag, ab, aw2, ab2,
                           rg2, rb2, rw3, rb3,
                           gw1, gg, gb, gw2, gb2,
                           out + r0, nloc);
    }
}